// Round 7
// baseline (182.521 us; speedup 1.0000x reference)
//
#include <hip/hip_runtime.h>
#include <hip/hip_fp16.h>

#define S    128
#define SS   (S * S)
#define PW   136             // padded dim: 128 + 2*PAD
#define PWH  (PW * PW)
#define PAD  4               // absorbs +/-2-step clip widening (proven R5/R6)
#define VOXN (PW * PW * PW)  // 2,515,456 (divisible by 256)

__device__ __forceinline__ float fetch_padded(const float* __restrict__ vol,
                                              int x, int y, int z) {
    const int xm = x - PAD, ym = y - PAD, zm = z - PAD;
    if (((unsigned)xm < 128u) & ((unsigned)ym < 128u) & ((unsigned)zm < 128u))
        return vol[(zm * S + ym) * S + xm];
    return 0.0f;
}

// ---------------------------------------------------------------------------
// Pass 1: max(vol) -> *smax (as float bits; vol is nonnegative).
// Commutative atomicMax -> deterministic.
// ---------------------------------------------------------------------------
__global__ __launch_bounds__(256) void vol_max_kernel(
    const float* __restrict__ vol, unsigned* __restrict__ smax)
{
    const int t = blockIdx.x * 256 + threadIdx.x;   // grid 512 -> stride 131072
    float m = 0.0f;
    for (int idx = t; idx < SS * S; idx += 256 * 512)
        m = fmaxf(m, vol[idx]);
    #pragma unroll
    for (int off = 32; off; off >>= 1)
        m = fmaxf(m, __shfl_down(m, off, 64));
    if ((threadIdx.x & 63) == 0)
        atomicMax(smax, __float_as_uint(m));
}

// ---------------------------------------------------------------------------
// Pass 2: three axis-permuted, zero-padded uint8 copies.
//   cp=0: fast=x  flat=(z*PW+y)*PW+x
//   cp=1: fast=y  flat=(z*PW+x)*PW+y
//   cp=2: fast=z  flat=(y*PW+x)*PW+z
// ---------------------------------------------------------------------------
__global__ __launch_bounds__(256) void pad_perm_u8_kernel(
    const float* __restrict__ vol, const unsigned* __restrict__ smax,
    unsigned char* __restrict__ pv)
{
    int t = blockIdx.x * 256 + threadIdx.x;     // [0, 3*VOXN)
    const float scale = fmaxf(__uint_as_float(*smax), 1e-20f);
    const float qs = 255.0f / scale;

    const int cp = t / VOXN;
    t -= cp * VOXN;
    const int c  = t % PW;
    const int r  = t / PW;
    const int bq = r % PW;
    const int a  = r / PW;

    int x, y, z;
    if (cp == 0)      { x = c;  y = bq; z = a; }
    else if (cp == 1) { x = bq; y = c;  z = a; }
    else              { x = bq; y = a;  z = c; }

    const float v = fetch_padded(vol, x, y, z);
    pv[cp * VOXN + (a * PW + bq) * PW + c] =
        (unsigned char)(fminf(v * qs + 0.5f, 255.0f));
}

// fp16 variant for the fallback tier.
__global__ __launch_bounds__(256) void pad_perm_h_kernel(
    const float* __restrict__ vol, __half* __restrict__ pv)
{
    int t = blockIdx.x * 256 + threadIdx.x;
    const int cp = t / VOXN;
    t -= cp * VOXN;
    const int c  = t % PW;
    const int r  = t / PW;
    const int bq = r % PW;
    const int a  = r / PW;
    int x, y, z;
    if (cp == 0)      { x = c;  y = bq; z = a; }
    else if (cp == 1) { x = bq; y = c;  z = a; }
    else              { x = bq; y = a;  z = c; }
    pv[cp * VOXN + (a * PW + bq) * PW + c] = __float2half(fetch_padded(vol, x, y, z));
}

// ---------------------------------------------------------------------------
// Ray setup (original axes). Clip window (3,132); <=2-step widening keeps all
// taps in [0,135]. Always in-bounds (proven R5/R6).
// ---------------------------------------------------------------------------
struct Ray {
    float ix0, iy0, iz0, ux, uy, uz;
    int kmin, kmax;
};

__device__ __forceinline__ Ray make_ray(const float* __restrict__ rot,
                                        int b, int i, int j, int seg) {
    const float* Rb = rot + b * 9;
    const float r00 = Rb[0], r01 = Rb[1], r02 = Rb[2];
    const float r10 = Rb[3], r11 = Rb[4], r12 = Rb[5];
    const float r20 = Rb[6], r21 = Rb[7], r22 = Rb[8];

    const float step = 2.0f / 127.0f;
    const float li = -1.0f + step * (float)i;
    const float lj = -1.0f + step * (float)j;

    Ray ry;
    ry.ix0 = (lj * r00 + li * r10 - r20 + 1.0f) * 63.5f + (float)PAD;
    ry.iy0 = (lj * r01 + li * r11 - r21 + 1.0f) * 63.5f + (float)PAD;
    ry.iz0 = (lj * r02 + li * r12 - r22 + 1.0f) * 63.5f + (float)PAD;
    ry.ux = r20; ry.uy = r21; ry.uz = r22;

    float klo = 0.0f, khi = 127.0f;
    const float lo = (float)(PAD - 1), hi = (float)(PAD + 128);
    if (fabsf(ry.ux) > 1e-7f) {
        float a = (lo - ry.ix0) / ry.ux, c = (hi - ry.ix0) / ry.ux;
        klo = fmaxf(klo, fminf(a, c)); khi = fminf(khi, fmaxf(a, c));
    } else if (ry.ix0 <= lo || ry.ix0 >= hi) { klo = 1e9f; khi = -1e9f; }
    if (fabsf(ry.uy) > 1e-7f) {
        float a = (lo - ry.iy0) / ry.uy, c = (hi - ry.iy0) / ry.uy;
        klo = fmaxf(klo, fminf(a, c)); khi = fminf(khi, fmaxf(a, c));
    } else if (ry.iy0 <= lo || ry.iy0 >= hi) { klo = 1e9f; khi = -1e9f; }
    if (fabsf(ry.uz) > 1e-7f) {
        float a = (lo - ry.iz0) / ry.uz, c = (hi - ry.iz0) / ry.uz;
        klo = fmaxf(klo, fminf(a, c)); khi = fminf(khi, fmaxf(a, c));
    } else if (ry.iz0 <= lo || ry.iz0 >= hi) { klo = 1e9f; khi = -1e9f; }

    ry.kmin = seg * 32; ry.kmax = seg * 32 + 31;   // split-k 4
    if (klo <= khi) {
        ry.kmin = max(ry.kmin, (int)floorf(klo) - 1);
        ry.kmax = min(ry.kmax, (int)ceilf(khi) + 1);
    } else {
        ry.kmax = ry.kmin - 1;
    }
    return ry;
}

// Axis-permutation of the ray to match copy `sel`'s layout.
__device__ __forceinline__ void permute_ray(const Ray& ry, int sel,
    float& px0, float& py0, float& pz0, float& pux, float& puy, float& puz)
{
    px0 = ry.ix0; py0 = ry.iy0; pz0 = ry.iz0;
    pux = ry.ux;  puy = ry.uy;  puz = ry.uz;
    if (sel == 1) {
        px0 = ry.iy0; py0 = ry.ix0;
        pux = ry.uy;  puy = ry.ux;
    } else if (sel == 2) {
        px0 = ry.iz0; py0 = ry.ix0; pz0 = ry.iy0;
        pux = ry.uz;  puy = ry.ux;  puz = ry.uy;
    }
}

// ---------------------------------------------------------------------------
// Main (uint8): one thread per (pixel, k-segment); 8x8 pixels per wave.
// Dequantization deferred to a single multiply at the end.
// ---------------------------------------------------------------------------
__global__ __launch_bounds__(256) void projector_u8(
    const float* __restrict__ rot,           // [16,3,3]
    const unsigned char* __restrict__ pv,    // [3][136^3]
    const unsigned* __restrict__ smax,
    float* __restrict__ out)                 // [16,1,128,128], pre-zeroed
{
    // Grid 4096 = b(16, outer) x seg(4) x tile(64)
    const int blk  = blockIdx.x;
    const int b    = blk >> 8;
    const int seg  = (blk >> 6) & 3;
    const int tile = blk & 63;
    const int tY   = tile >> 3, tX = tile & 7;

    const int wave = threadIdx.x >> 6;
    const int lane = threadIdx.x & 63;
    const int i = tY * 16 + (wave >> 1) * 8 + (lane >> 3);
    const int j = tX * 16 + (wave & 1) * 8 + (lane & 7);

    const Ray ry = make_ray(rot, b, i, j, seg);

    const float ax = fabsf(ry.ux), ay = fabsf(ry.uy), az = fabsf(ry.uz);
    const int sel = (ax <= ay && ax <= az) ? 0 : ((ay <= az) ? 1 : 2);
    float px0, py0, pz0, pux, puy, puz;
    permute_ray(ry, sel, px0, py0, pz0, pux, puy, puz);
    const unsigned char* __restrict__ vol = pv + sel * VOXN;

    float acc = 0.0f;
    #pragma unroll 2
    for (int k = ry.kmin; k <= ry.kmax; ++k) {
        const float kk = (float)k;
        const float ix = fmaf(kk, pux, px0);
        const float iy = fmaf(kk, puy, py0);
        const float iz = fmaf(kk, puz, pz0);

        const float xf = floorf(ix), yf = floorf(iy), zf = floorf(iz);
        const float fx = ix - xf, fy = iy - yf, fz = iz - zf;
        const int xi = (int)xf, yi = (int)yf, zi = (int)zf;

        const unsigned char* p = vol + (zi * PW + yi) * PW + xi;
        const float v000 = (float)p[0],        v001 = (float)p[1];
        const float v010 = (float)p[PW],       v011 = (float)p[PW + 1];
        const float v100 = (float)p[PWH],      v101 = (float)p[PWH + 1];
        const float v110 = (float)p[PWH + PW], v111 = (float)p[PWH + PW + 1];

        const float c00 = fmaf(fx, v001 - v000, v000);
        const float c01 = fmaf(fx, v011 - v010, v010);
        const float c10 = fmaf(fx, v101 - v100, v100);
        const float c11 = fmaf(fx, v111 - v110, v110);
        const float c0  = fmaf(fy, c01 - c00, c00);
        const float c1  = fmaf(fy, c11 - c10, c10);
        acc += fmaf(fz, c1 - c0, c0);
    }

    const float dq = fmaxf(__uint_as_float(*smax), 1e-20f) * (1.0f / 255.0f);
    atomicAdd(&out[(b << 14) + (i << 7) + j], acc * dq);
}

// ---------------------------------------------------------------------------
// Fallback tier 2: fp16 3-copy (R6, passed).
// ---------------------------------------------------------------------------
__global__ __launch_bounds__(256) void projector_h3(
    const float* __restrict__ rot, const __half* __restrict__ pv,
    float* __restrict__ out)
{
    const int blk  = blockIdx.x;
    const int b    = blk >> 8;
    const int seg  = (blk >> 6) & 3;
    const int tile = blk & 63;
    const int tY   = tile >> 3, tX = tile & 7;
    const int wave = threadIdx.x >> 6;
    const int lane = threadIdx.x & 63;
    const int i = tY * 16 + (wave >> 1) * 8 + (lane >> 3);
    const int j = tX * 16 + (wave & 1) * 8 + (lane & 7);

    const Ray ry = make_ray(rot, b, i, j, seg);
    const float ax = fabsf(ry.ux), ay = fabsf(ry.uy), az = fabsf(ry.uz);
    const int sel = (ax <= ay && ax <= az) ? 0 : ((ay <= az) ? 1 : 2);
    float px0, py0, pz0, pux, puy, puz;
    permute_ray(ry, sel, px0, py0, pz0, pux, puy, puz);
    const __half* __restrict__ vol = pv + sel * VOXN;

    float acc = 0.0f;
    #pragma unroll 2
    for (int k = ry.kmin; k <= ry.kmax; ++k) {
        const float kk = (float)k;
        const float ix = fmaf(kk, pux, px0);
        const float iy = fmaf(kk, puy, py0);
        const float iz = fmaf(kk, puz, pz0);
        const float xf = floorf(ix), yf = floorf(iy), zf = floorf(iz);
        const float fx = ix - xf, fy = iy - yf, fz = iz - zf;
        const int xi = (int)xf, yi = (int)yf, zi = (int)zf;
        const __half* p = vol + (zi * PW + yi) * PW + xi;
        const float v000 = __half2float(p[0]),        v001 = __half2float(p[1]);
        const float v010 = __half2float(p[PW]),       v011 = __half2float(p[PW + 1]);
        const float v100 = __half2float(p[PWH]),      v101 = __half2float(p[PWH + 1]);
        const float v110 = __half2float(p[PWH + PW]), v111 = __half2float(p[PWH + PW + 1]);
        const float c00 = fmaf(fx, v001 - v000, v000);
        const float c01 = fmaf(fx, v011 - v010, v010);
        const float c10 = fmaf(fx, v101 - v100, v100);
        const float c11 = fmaf(fx, v111 - v110, v110);
        const float c0  = fmaf(fy, c01 - c00, c00);
        const float c1  = fmaf(fy, c11 - c10, c10);
        acc += fmaf(fz, c1 - c0, c0);
    }
    atomicAdd(&out[(b << 14) + (i << 7) + j], acc);
}

// ---------------------------------------------------------------------------
// Fallback tier 3: direct fp32, no workspace (R1, passed).
// ---------------------------------------------------------------------------
__global__ __launch_bounds__(256) void projector_f32(
    const float* __restrict__ rot, const float* __restrict__ vol,
    float* __restrict__ out)
{
    const int pix = blockIdx.x * 256 + threadIdx.x;
    const int b = pix >> 14, rem = pix & 16383;
    const int i = rem >> 7, j = rem & 127;
    const float* Rb = rot + b * 9;
    const float step = 2.0f / 127.0f;
    const float li = -1.0f + step * (float)i;
    const float lj = -1.0f + step * (float)j;
    const float ix0 = (lj * Rb[0] + li * Rb[3] - Rb[6] + 1.0f) * 63.5f;
    const float iy0 = (lj * Rb[1] + li * Rb[4] - Rb[7] + 1.0f) * 63.5f;
    const float iz0 = (lj * Rb[2] + li * Rb[5] - Rb[8] + 1.0f) * 63.5f;
    const float ux = Rb[6], uy = Rb[7], uz = Rb[8];
    float acc = 0.0f;
    for (int k = 0; k < 128; ++k) {
        const float kk = (float)k;
        const float ix = fmaf(kk, ux, ix0), iy = fmaf(kk, uy, iy0), iz = fmaf(kk, uz, iz0);
        const float xf = floorf(ix), yf = floorf(iy), zf = floorf(iz);
        const float fx = ix - xf, fy = iy - yf, fz = iz - zf;
        const int x0 = (int)xf, y0 = (int)yf, z0 = (int)zf;
        const int x1 = x0 + 1, y1 = y0 + 1, z1 = z0 + 1;
        const bool vx0 = (unsigned)x0 < 128u, vx1 = (unsigned)x1 < 128u;
        const bool vy0 = (unsigned)y0 < 128u, vy1 = (unsigned)y1 < 128u;
        const bool vz0 = (unsigned)z0 < 128u, vz1 = (unsigned)z1 < 128u;
        const float v000 = (vx0 && vy0 && vz0) ? vol[(z0 * S + y0) * S + x0] : 0.0f;
        const float v001 = (vx1 && vy0 && vz0) ? vol[(z0 * S + y0) * S + x1] : 0.0f;
        const float v010 = (vx0 && vy1 && vz0) ? vol[(z0 * S + y1) * S + x0] : 0.0f;
        const float v011 = (vx1 && vy1 && vz0) ? vol[(z0 * S + y1) * S + x1] : 0.0f;
        const float v100 = (vx0 && vy0 && vz1) ? vol[(z1 * S + y0) * S + x0] : 0.0f;
        const float v101 = (vx1 && vy0 && vz1) ? vol[(z1 * S + y0) * S + x1] : 0.0f;
        const float v110 = (vx0 && vy1 && vz1) ? vol[(z1 * S + y1) * S + x0] : 0.0f;
        const float v111 = (vx1 && vy1 && vz1) ? vol[(z1 * S + y1) * S + x1] : 0.0f;
        const float c00 = v000 + fx * (v001 - v000);
        const float c01 = v010 + fx * (v011 - v010);
        const float c10 = v100 + fx * (v101 - v100);
        const float c11 = v110 + fx * (v111 - v110);
        const float c0 = c00 + fy * (c01 - c00);
        const float c1 = c10 + fy * (c11 - c10);
        acc += c0 + fz * (c1 - c0);
    }
    out[pix] = acc;
}

extern "C" void kernel_launch(void* const* d_in, const int* in_sizes, int n_in,
                              void* d_out, int out_size, void* d_ws, size_t ws_size,
                              hipStream_t stream) {
    const float* rot = (const float*)d_in[0];   // [16,3,3]
    const float* vol = (const float*)d_in[1];   // [128^3] fp32
    float* out = (float*)d_out;                 // [16*128*128]

    const size_t need_u8 = 256 + (size_t)3 * VOXN;               // ~7.8 MB
    const size_t need_h3 = (size_t)3 * VOXN * sizeof(__half);    // ~15.1 MB

    if (ws_size >= need_u8) {
        unsigned*      smax = (unsigned*)d_ws;
        unsigned char* pv   = (unsigned char*)d_ws + 256;
        hipMemsetAsync(out, 0, (size_t)out_size * sizeof(float), stream);
        hipMemsetAsync(smax, 0, sizeof(unsigned), stream);
        vol_max_kernel<<<512, 256, 0, stream>>>(vol, smax);
        pad_perm_u8_kernel<<<3 * (VOXN / 256), 256, 0, stream>>>(vol, smax, pv);
        projector_u8<<<4096, 256, 0, stream>>>(rot, pv, smax, out);
    } else if (ws_size >= need_h3) {
        __half* pv = (__half*)d_ws;
        hipMemsetAsync(out, 0, (size_t)out_size * sizeof(float), stream);
        pad_perm_h_kernel<<<3 * (VOXN / 256), 256, 0, stream>>>(vol, pv);
        projector_h3<<<4096, 256, 0, stream>>>(rot, pv, out);
    } else {
        projector_f32<<<(16 * SS) / 256, 256, 0, stream>>>(rot, vol, out);
    }
}